// Round 12
// baseline (2060.228 us; speedup 1.0000x reference)
//
#include <hip/hip_runtime.h>
#include <math.h>

#define BS   2048
#define SEQ  50
#define NPOS (BS * SEQ)

__device__ __forceinline__ float sigf(float x) { return 1.0f / (1.0f + __expf(-x)); }
__device__ __forceinline__ float tanhfast(float x) {
    float e = __expf(2.0f * x);
    return 1.0f - 2.0f / (e + 1.0f);
}

// ---- macro toolkit: named-SSA values only (NO private arrays) -------------
#define FMA4(A, X, W) \
    A = fmaf((X).x, (W).x, A); A = fmaf((X).y, (W).y, A); \
    A = fmaf((X).z, (W).z, A); A = fmaf((X).w, (W).w, A);

#define LD16(P, N) \
    float4 N##0=(P)[0],  N##1=(P)[1],  N##2=(P)[2],  N##3=(P)[3], \
           N##4=(P)[4],  N##5=(P)[5],  N##6=(P)[6],  N##7=(P)[7], \
           N##8=(P)[8],  N##9=(P)[9],  N##10=(P)[10],N##11=(P)[11], \
           N##12=(P)[12],N##13=(P)[13],N##14=(P)[14],N##15=(P)[15];

// ---------------------------------------------------------------------------
// prep_w (R10 verbatim): transpose W_ih/W_hh into wave-contiguous layouts.
//   wiT[(g*4+kk)*512 + t] = W_ih[(4*(t>>2)+g)*64  + (t&3)*16 + kk*4 ..+3]
//   whT[(g*8+kk)*512 + t] = W_hh[(4*(t>>2)+g)*128 + (t&3)*32 + kk*4 ..+3]
// ---------------------------------------------------------------------------
__global__ __launch_bounds__(512) void prep_w(
    const float* __restrict__ Wih, const float* __restrict__ Whh,
    float4* __restrict__ wiT, float4* __restrict__ whT)
{
    const int t = threadIdx.x;
    const int gq = t >> 2, kq = t & 3;
    const int b = blockIdx.x;
    if (b < 16) {
        const int g = b >> 2, kk = b & 3;
        wiT[b * 512 + t] = *(const float4*)&Wih[(4*gq + g) * 64 + kq * 16 + kk * 4];
    } else {
        const int c = b - 16;
        const int g = c >> 3, kk = c & 7;
        whT[c * 512 + t] = *(const float4*)&Whh[(4*gq + g) * 128 + kq * 32 + kk * 4];
    }
}

// ---------------------------------------------------------------------------
// Kernel A v2: split Q-side / V-side across 2 waves (128-thr blocks).
//   wave 0 (t<64):  holds Wq row (16 f4), computes edges 0-4, key, QK^T,
//                   masked softmax, writes normalized att to LDS.
//   wave 1 (t>=64): holds Wv row (16 f4), computes edges 5-8, V proj,
//                   att-weighted combine, writes ctx.
// Per-thread resident weights 64 VGPR (was 128) -> total demand ~125 < the
// compiler's default 128 budget (R1-R5: budget is pinned at 128; fit it).
// Occupancy doubles to 4 waves/SIMD vs the R6 wq+wv-resident design.
// Edge-pair dot (2 FMA chains/wave) covers the 4-cyc dep latency.
// ---------------------------------------------------------------------------
#define EDGEM(e) { float v_ = bfr + wfe##e; \
    v_ = fmaf(s_seq[(e)*6+0], wf0, v_); \
    v_ = fmaf(s_seq[(e)*6+1], wf1, v_); \
    v_ = fmaf(s_seq[(e)*6+2], wf2, v_); \
    v_ = fmaf(s_seq[(e)*6+3], wf3, v_); \
    v_ = fmaf(s_seq[(e)*6+4], wf4, v_); \
    v_ = fmaf(s_seq[(e)*6+5], wf5, v_); \
    v_ = fmaf(s_et[(e)*4+0],  wf6, v_); \
    v_ = fmaf(s_et[(e)*4+1],  wf7, v_); \
    v_ = fmaf(s_et[(e)*4+2],  wf8, v_); \
    v_ = fmaf(s_et[(e)*4+3],  wf9, v_); \
    s_edge[(e)*64 + o] = v_; }

#define PAIRQ(ea, eb) { \
    const float4* pa_ = (const float4*)&s_edge[(ea)*64]; \
    const float4* pb_ = (const float4*)&s_edge[(eb)*64]; \
    float qa_ = 0.f, qb_ = 0.f; float4 xa_, xb_; \
    xa_=pa_[0];  xb_=pb_[0];  FMA4(qa_,xa_,wz0)  FMA4(qb_,xb_,wz0) \
    xa_=pa_[1];  xb_=pb_[1];  FMA4(qa_,xa_,wz1)  FMA4(qb_,xb_,wz1) \
    xa_=pa_[2];  xb_=pb_[2];  FMA4(qa_,xa_,wz2)  FMA4(qb_,xb_,wz2) \
    xa_=pa_[3];  xb_=pb_[3];  FMA4(qa_,xa_,wz3)  FMA4(qb_,xb_,wz3) \
    xa_=pa_[4];  xb_=pb_[4];  FMA4(qa_,xa_,wz4)  FMA4(qb_,xb_,wz4) \
    xa_=pa_[5];  xb_=pb_[5];  FMA4(qa_,xa_,wz5)  FMA4(qb_,xb_,wz5) \
    xa_=pa_[6];  xb_=pb_[6];  FMA4(qa_,xa_,wz6)  FMA4(qb_,xb_,wz6) \
    xa_=pa_[7];  xb_=pb_[7];  FMA4(qa_,xa_,wz7)  FMA4(qb_,xb_,wz7) \
    xa_=pa_[8];  xb_=pb_[8];  FMA4(qa_,xa_,wz8)  FMA4(qb_,xb_,wz8) \
    xa_=pa_[9];  xb_=pb_[9];  FMA4(qa_,xa_,wz9)  FMA4(qb_,xb_,wz9) \
    xa_=pa_[10]; xb_=pb_[10]; FMA4(qa_,xa_,wz10) FMA4(qb_,xb_,wz10) \
    xa_=pa_[11]; xb_=pb_[11]; FMA4(qa_,xa_,wz11) FMA4(qb_,xb_,wz11) \
    xa_=pa_[12]; xb_=pb_[12]; FMA4(qa_,xa_,wz12) FMA4(qb_,xb_,wz12) \
    xa_=pa_[13]; xb_=pb_[13]; FMA4(qa_,xa_,wz13) FMA4(qb_,xb_,wz13) \
    xa_=pa_[14]; xb_=pb_[14]; FMA4(qa_,xa_,wz14) FMA4(qb_,xb_,wz14) \
    xa_=pa_[15]; xb_=pb_[15]; FMA4(qa_,xa_,wz15) FMA4(qb_,xb_,wz15) \
    r##ea = bz + qa_; r##eb = bz + qb_; }

#define SINGQ(ea) { \
    const float4* pa_ = (const float4*)&s_edge[(ea)*64]; \
    float qa_ = 0.f, qc_ = 0.f; float4 xa_; \
    xa_=pa_[0];  FMA4(qa_,xa_,wz0)   xa_=pa_[1];  FMA4(qc_,xa_,wz1) \
    xa_=pa_[2];  FMA4(qa_,xa_,wz2)   xa_=pa_[3];  FMA4(qc_,xa_,wz3) \
    xa_=pa_[4];  FMA4(qa_,xa_,wz4)   xa_=pa_[5];  FMA4(qc_,xa_,wz5) \
    xa_=pa_[6];  FMA4(qa_,xa_,wz6)   xa_=pa_[7];  FMA4(qc_,xa_,wz7) \
    xa_=pa_[8];  FMA4(qa_,xa_,wz8)   xa_=pa_[9];  FMA4(qc_,xa_,wz9) \
    xa_=pa_[10]; FMA4(qa_,xa_,wz10)  xa_=pa_[11]; FMA4(qc_,xa_,wz11) \
    xa_=pa_[12]; FMA4(qa_,xa_,wz12)  xa_=pa_[13]; FMA4(qc_,xa_,wz13) \
    xa_=pa_[14]; FMA4(qa_,xa_,wz14)  xa_=pa_[15]; FMA4(qc_,xa_,wz15) \
    r##ea = bz + qa_ + qc_; }

#define ATTR(e) { float a_ = key * r##e; \
    a_ += __shfl_xor(a_, 8, 16); a_ += __shfl_xor(a_, 4, 16); \
    a_ += __shfl_xor(a_, 2, 16); a_ += __shfl_xor(a_, 1, 16); \
    r##e = a_ * 0.25f; }

__global__ __launch_bounds__(128)
void edge_attn_ctx(
    const float* __restrict__ seqs,   // [BS,SEQ,3,3,6]
    const float* __restrict__ ets,    // [BS,SEQ,3,3,4]
    const int*   __restrict__ masks,  // [BS,SEQ,3,3]
    const float* __restrict__ Wf, const float* __restrict__ bf,
    const float* __restrict__ Wk, const float* __restrict__ bk,
    const float* __restrict__ Wq, const float* __restrict__ bq,
    const float* __restrict__ Wv, const float* __restrict__ bv,
    float* __restrict__ ctx)          // [BS,SEQ,64]
{
    const int t = threadIdx.x;
    const int w = t >> 6;             // 0 = Q-side wave, 1 = V-side wave
    const int o = t & 63;             // output channel

    // this wave's matrix row (Wq for wave 0, Wv for wave 1): 16 f4 = 64 VGPR
    const float* Wz = (w == 0) ? Wq : Wv;
    const float4* zp = (const float4*)&Wz[o * 64];
    LD16(zp, wz)
    const float bz = (w == 0) ? bq[o] : bv[o];

    // fusion weights (both waves compute edges)
    const float* wfp = &Wf[o * 19];
    float wf0=wfp[0], wf1=wfp[1], wf2=wfp[2], wf3=wfp[3], wf4=wfp[4], wf5=wfp[5],
          wf6=wfp[6], wf7=wfp[7], wf8=wfp[8], wf9=wfp[9];
    float wfe0=wfp[10], wfe1=wfp[11], wfe2=wfp[12], wfe3=wfp[13], wfe4=wfp[14],
          wfe5=wfp[15], wfe6=wfp[16], wfe7=wfp[17], wfe8=wfp[18];
    const float bfr = bf[o];
    // key weights (used by wave 0 only; 7 regs, loaded by all)
    const float* wkp = &Wk[o * 6];
    const float wk0=wkp[0], wk1=wkp[1], wk2=wkp[2], wk3=wkp[3], wk4=wkp[4], wk5=wkp[5];
    const float bkr = bk[o];

    __shared__ float s_seq[54];
    __shared__ float s_et[36];
    __shared__ int   s_mask[9];
    __shared__ float s_edge[9 * 64];
    __shared__ float s_att[36];       // [head*9 + e], normalized

    for (int p = blockIdx.x; p < NPOS; p += gridDim.x) {
        if (t < 54)      s_seq[t]       = seqs[p * 54 + t];
        else if (t < 90) s_et[t - 54]   = ets[p * 36 + (t - 54)];
        else if (t < 99) s_mask[t - 90] = masks[p * 9 + (t - 90)];
        __syncthreads();

        float key = 0.f;
        if (w == 0) {
            EDGEM(0) EDGEM(1) EDGEM(2) EDGEM(3) EDGEM(4)
            key = bkr;
            key = fmaf(s_seq[24], wk0, key);
            key = fmaf(s_seq[25], wk1, key);
            key = fmaf(s_seq[26], wk2, key);
            key = fmaf(s_seq[27], wk3, key);
            key = fmaf(s_seq[28], wk4, key);
            key = fmaf(s_seq[29], wk5, key);
        } else {
            EDGEM(5) EDGEM(6) EDGEM(7) EDGEM(8)
        }
        __syncthreads();

        // projection: wave 0 -> q[e], wave 1 -> v[e]  (9 named scalars)
        float r0, r1, r2, r3, r4, r5, r6, r7, r8;
        PAIRQ(0, 1) PAIRQ(2, 3) PAIRQ(4, 5) PAIRQ(6, 7) SINGQ(8)

        if (w == 0) {
            // att = (key . q) / sqrt(16), per head (16-lane groups)
            ATTR(0) ATTR(1) ATTR(2) ATTR(3) ATTR(4) ATTR(5) ATTR(6) ATTR(7) ATTR(8)
            // mask + softmax over the 9 edges
            r0 = (s_mask[0] == 0) ? -1.0e10f : r0;
            r1 = (s_mask[1] == 0) ? -1.0e10f : r1;
            r2 = (s_mask[2] == 0) ? -1.0e10f : r2;
            r3 = (s_mask[3] == 0) ? -1.0e10f : r3;
            r4 = (s_mask[4] == 0) ? -1.0e10f : r4;
            r5 = (s_mask[5] == 0) ? -1.0e10f : r5;
            r6 = (s_mask[6] == 0) ? -1.0e10f : r6;
            r7 = (s_mask[7] == 0) ? -1.0e10f : r7;
            r8 = (s_mask[8] == 0) ? -1.0e10f : r8;
            float mx = fmaxf(r0, r1);
            mx = fmaxf(mx, r2); mx = fmaxf(mx, r3); mx = fmaxf(mx, r4);
            mx = fmaxf(mx, r5); mx = fmaxf(mx, r6); mx = fmaxf(mx, r7);
            mx = fmaxf(mx, r8);
            r0 = __expf(r0 - mx); r1 = __expf(r1 - mx); r2 = __expf(r2 - mx);
            r3 = __expf(r3 - mx); r4 = __expf(r4 - mx); r5 = __expf(r5 - mx);
            r6 = __expf(r6 - mx); r7 = __expf(r7 - mx); r8 = __expf(r8 - mx);
            float inv = 1.f / (r0+r1+r2+r3+r4+r5+r6+r7+r8);
            if ((o & 15) == 0) {
                float* ap = &s_att[(o >> 4) * 9];
                ap[0] = r0 * inv; ap[1] = r1 * inv; ap[2] = r2 * inv;
                ap[3] = r3 * inv; ap[4] = r4 * inv; ap[5] = r5 * inv;
                ap[6] = r6 * inv; ap[7] = r7 * inv; ap[8] = r8 * inv;
            }
        }
        __syncthreads();

        if (w == 1) {
            const float* ap = &s_att[(o >> 4) * 9];
            float acc;
            acc = ap[0] * r0;
            acc = fmaf(ap[1], r1, acc);
            acc = fmaf(ap[2], r2, acc);
            acc = fmaf(ap[3], r3, acc);
            acc = fmaf(ap[4], r4, acc);
            acc = fmaf(ap[5], r5, acc);
            acc = fmaf(ap[6], r6, acc);
            acc = fmaf(ap[7], r7, acc);
            acc = fmaf(ap[8], r8, acc);
            ctx[p * 64 + o] = acc;
        }
        __syncthreads();
    }
}

// ---------------------------------------------------------------------------
// Kernel C (R10 verbatim — proven 484 us, VGPR 88, WRITE 512 KB):
// G=4 x S=4, R=8, 256 blk x 512 thr; coalesced transposed weight stream with
// DYNAMIC (kk+s)&mask rotation. Do NOT staticize the addressing (R11: the
// scheduler hoists/pipelines static-offset loads -> 128 VGPR + 185 MB spill).
// ---------------------------------------------------------------------------
#define XROW 80    // floats per s_x row (quarters of 16 at cols 0/20/40/60)
#define HROWF 144  // floats per s_h row (quarters of 32 at cols 0/36/72/108)
#define SGS  516   // s_g row stride (floats)

#define XG(kk) { \
    const int kk2 = ((kk) + s) & 3; \
    const int wb = kk2 * 512 + t; \
    float4 w0_ = wiT[0*2048 + wb]; \
    float4 w1_ = wiT[1*2048 + wb]; \
    float4 w2_ = wiT[2*2048 + wb]; \
    float4 w3_ = wiT[3*2048 + wb]; \
    float4 x_; \
    x_ = sx4[0*20 + kq5 + kk2]; FMA4(A00,x_,w0_) FMA4(A10,x_,w1_) FMA4(A20,x_,w2_) FMA4(A30,x_,w3_) \
    x_ = sx4[1*20 + kq5 + kk2]; FMA4(A01,x_,w0_) FMA4(A11,x_,w1_) FMA4(A21,x_,w2_) FMA4(A31,x_,w3_) \
    x_ = sx4[2*20 + kq5 + kk2]; FMA4(A02,x_,w0_) FMA4(A12,x_,w1_) FMA4(A22,x_,w2_) FMA4(A32,x_,w3_) \
    x_ = sx4[3*20 + kq5 + kk2]; FMA4(A03,x_,w0_) FMA4(A13,x_,w1_) FMA4(A23,x_,w2_) FMA4(A33,x_,w3_) \
    x_ = sx4[4*20 + kq5 + kk2]; FMA4(A04,x_,w0_) FMA4(A14,x_,w1_) FMA4(A24,x_,w2_) FMA4(A34,x_,w3_) \
    x_ = sx4[5*20 + kq5 + kk2]; FMA4(A05,x_,w0_) FMA4(A15,x_,w1_) FMA4(A25,x_,w2_) FMA4(A35,x_,w3_) \
    x_ = sx4[6*20 + kq5 + kk2]; FMA4(A06,x_,w0_) FMA4(A16,x_,w1_) FMA4(A26,x_,w2_) FMA4(A36,x_,w3_) \
    x_ = sx4[7*20 + kq5 + kk2]; FMA4(A07,x_,w0_) FMA4(A17,x_,w1_) FMA4(A27,x_,w2_) FMA4(A37,x_,w3_) }

#define HG(kk) { \
    const int kk2 = ((kk) + s) & 7; \
    const int wb = kk2 * 512 + t; \
    float4 w0_ = whT[0*4096 + wb]; \
    float4 w1_ = whT[1*4096 + wb]; \
    float4 w2_ = whT[2*4096 + wb]; \
    float4 w3_ = whT[3*4096 + wb]; \
    float4 h_; \
    h_ = sh4[0*36 + kq9 + kk2]; FMA4(A00,h_,w0_) FMA4(A10,h_,w1_) FMA4(A20,h_,w2_) FMA4(A30,h_,w3_) \
    h_ = sh4[1*36 + kq9 + kk2]; FMA4(A01,h_,w0_) FMA4(A11,h_,w1_) FMA4(A21,h_,w2_) FMA4(A31,h_,w3_) \
    h_ = sh4[2*36 + kq9 + kk2]; FMA4(A02,h_,w0_) FMA4(A12,h_,w1_) FMA4(A22,h_,w2_) FMA4(A32,h_,w3_) \
    h_ = sh4[3*36 + kq9 + kk2]; FMA4(A03,h_,w0_) FMA4(A13,h_,w1_) FMA4(A23,h_,w2_) FMA4(A33,h_,w3_) \
    h_ = sh4[4*36 + kq9 + kk2]; FMA4(A04,h_,w0_) FMA4(A14,h_,w1_) FMA4(A24,h_,w2_) FMA4(A34,h_,w3_) \
    h_ = sh4[5*36 + kq9 + kk2]; FMA4(A05,h_,w0_) FMA4(A15,h_,w1_) FMA4(A25,h_,w2_) FMA4(A35,h_,w3_) \
    h_ = sh4[6*36 + kq9 + kk2]; FMA4(A06,h_,w0_) FMA4(A16,h_,w1_) FMA4(A26,h_,w2_) FMA4(A36,h_,w3_) \
    h_ = sh4[7*36 + kq9 + kk2]; FMA4(A07,h_,w0_) FMA4(A17,h_,w1_) FMA4(A27,h_,w2_) FMA4(A37,h_,w3_) }

#define RED2(A) A += __shfl_xor(A, 1); A += __shfl_xor(A, 2);
#define SELL(g) (kq == 0 ? A##g##0 : kq == 1 ? A##g##1 : kq == 2 ? A##g##2 : A##g##3)
#define SELH(g) (kq == 0 ? A##g##4 : kq == 1 ? A##g##5 : kq == 2 ? A##g##6 : A##g##7)

__global__ __launch_bounds__(512)
void lstm_out(
    const float*  __restrict__ ctx,   // [BS,SEQ,64]
    const float4* __restrict__ wiT,   // [(g*4+kk)*512 + t]
    const float4* __restrict__ whT,   // [(g*8+kk)*512 + t]
    const float*  __restrict__ b_ih, const float* __restrict__ b_hh,
    const float*  __restrict__ W_out, const float* __restrict__ b_out,
    float* __restrict__ out)          // [BS,64]
{
    const int t    = threadIdx.x;
    const int gq   = t >> 2;          // gate quad 0..127 -> gates 4gq..4gq+3
    const int kq   = t & 3;           // k-quarter
    const int kq5  = kq * 5;          // x quarter offset (float4s)
    const int kq9  = kq * 9;          // h quarter offset (float4s)
    const int row0 = blockIdx.x * 8;
    const int r2   = t >> 6;          // pointwise/staging row 0..7
    const int m    = t & 63;          // pointwise elem (m and m+64)

    // pointwise biases (gate order i,f,g,o = rows 0/128/256/384)
    const float bi0 = b_ih[m]       + b_hh[m];
    const float bf0 = b_ih[128 + m] + b_hh[128 + m];
    const float bg0 = b_ih[256 + m] + b_hh[256 + m];
    const float bo0 = b_ih[384 + m] + b_hh[384 + m];
    const float bi1 = b_ih[64 + m]  + b_hh[64 + m];
    const float bf1 = b_ih[192 + m] + b_hh[192 + m];
    const float bg1 = b_ih[320 + m] + b_hh[320 + m];
    const float bo1 = b_ih[448 + m] + b_hh[448 + m];

    __shared__ float s_x[8 * XROW];
    __shared__ float s_h[8 * HROWF];
    __shared__ float s_g[8 * SGS];

    const float4* sx4 = (const float4*)s_x;
    const float4* sh4 = (const float4*)s_h;

    const int xcol  = r2 * XROW + (m >> 4) * 20 + (m & 15);
    const int hcol0 = r2 * HROWF + (m >> 5) * 36 + (m & 31);
    const int hcol1 = r2 * HROWF + (2 + (m >> 5)) * 36 + (m & 31);

    float c0 = 0.f, c1 = 0.f;

    for (int s = 0; s < SEQ; ++s) {
        s_x[xcol] = ctx[((row0 + r2) * SEQ + s) * 64 + m];
        __syncthreads();

        float A00=0.f,A01=0.f,A02=0.f,A03=0.f,A04=0.f,A05=0.f,A06=0.f,A07=0.f;
        float A10=0.f,A11=0.f,A12=0.f,A13=0.f,A14=0.f,A15=0.f,A16=0.f,A17=0.f;
        float A20=0.f,A21=0.f,A22=0.f,A23=0.f,A24=0.f,A25=0.f,A26=0.f,A27=0.f;
        float A30=0.f,A31=0.f,A32=0.f,A33=0.f,A34=0.f,A35=0.f,A36=0.f,A37=0.f;

        XG(0) XG(1) XG(2) XG(3)
        if (s > 0) {
            HG(0) HG(1) HG(2) HG(3) HG(4) HG(5) HG(6) HG(7)
        }

        RED2(A00) RED2(A01) RED2(A02) RED2(A03) RED2(A04) RED2(A05) RED2(A06) RED2(A07)
        RED2(A10) RED2(A11) RED2(A12) RED2(A13) RED2(A14) RED2(A15) RED2(A16) RED2(A17)
        RED2(A20) RED2(A21) RED2(A22) RED2(A23) RED2(A24) RED2(A25) RED2(A26) RED2(A27)
        RED2(A30) RED2(A31) RED2(A32) RED2(A33) RED2(A34) RED2(A35) RED2(A36) RED2(A37)

        {   // lane kq writes rows kq and kq+4, gates 4gq..4gq+3 (b128 each)
            float4 glo = make_float4(SELL(0), SELL(1), SELL(2), SELL(3));
            float4 ghi = make_float4(SELH(0), SELH(1), SELH(2), SELH(3));
            *(float4*)&s_g[kq * SGS + (gq << 2)]       = glo;
            *(float4*)&s_g[(kq + 4) * SGS + (gq << 2)] = ghi;
        }
        __syncthreads();

        {   // pointwise for (r2, m) and (r2, m+64); c-state in registers
            const float* g0 = &s_g[r2 * SGS];
            float ig = sigf(g0[m] + bi0);
            float fg = sigf(g0[128 + m] + bf0);
            float gt = tanhfast(g0[256 + m] + bg0);
            float og = sigf(g0[384 + m] + bo0);
            c0 = fmaf(fg, c0, ig * gt);
            s_h[hcol0] = og * tanhfast(c0);

            float ih = sigf(g0[64 + m] + bi1);
            float fh = sigf(g0[192 + m] + bf1);
            float gh = tanhfast(g0[320 + m] + bg1);
            float oh = sigf(g0[448 + m] + bo1);
            c1 = fmaf(fh, c1, ih * gh);
            s_h[hcol1] = oh * tanhfast(c1);
        }
        __syncthreads();
    }

    // epilogue: out[row0+r2][m] = b_out[m] + h[r2] . W_out[m]
    {
        float acc = b_out[m];
        const float4* wp = (const float4*)&W_out[m * 128];
        #pragma unroll
        for (int q = 0; q < 4; ++q)
            #pragma unroll
            for (int i = 0; i < 8; ++i) {
                float4 h4 = sh4[r2 * 36 + q * 9 + i];   // broadcast read
                float4 w4 = wp[q * 8 + i];
                FMA4(acc, h4, w4)
            }
        out[(row0 + r2) * 64 + m] = acc;
    }
}

// ---------------------------------------------------------------------------
extern "C" void kernel_launch(void* const* d_in, const int* in_sizes, int n_in,
                              void* d_out, int out_size, void* d_ws, size_t ws_size,
                              hipStream_t stream) {
    (void)in_sizes; (void)n_in; (void)out_size; (void)ws_size;
    const float* seqs  = (const float*)d_in[0];
    const float* ets   = (const float*)d_in[1];
    const int*   masks = (const int*)d_in[2];
    const float* Wf  = (const float*)d_in[3];
    const float* bf  = (const float*)d_in[4];
    const float* Wk  = (const float*)d_in[5];
    const float* bk  = (const float*)d_in[6];
    const float* Wq  = (const float*)d_in[7];
    const float* bq  = (const float*)d_in[8];
    const float* Wv  = (const float*)d_in[9];
    const float* bv  = (const float*)d_in[10];
    const float* Wih = (const float*)d_in[11];
    const float* Whh = (const float*)d_in[12];
    const float* bih = (const float*)d_in[13];
    const float* bhh = (const float*)d_in[14];
    const float* Wo  = (const float*)d_in[15];
    const float* bo  = (const float*)d_in[16];

    // ws layout: wiT 128K | whT 256K | ctx 26.2M
    char* ws = (char*)d_ws;
    float4* wiT = (float4*)(ws);
    float4* whT = (float4*)(ws + 131072);
    float*  ctx = (float*) (ws + 131072 + 262144);

    hipLaunchKernelGGL(prep_w, dim3(48), dim3(512), 0, stream,
                       Wih, Whh, wiT, whT);
    hipLaunchKernelGGL(edge_attn_ctx, dim3(4096), dim3(128), 0, stream,
                       seqs, ets, masks, Wf, bf, Wk, bk, Wq, bq, Wv, bv, ctx);
    hipLaunchKernelGGL(lstm_out, dim3(256), dim3(512), 0, stream,
                       ctx, wiT, whT, bih, bhh, Wo, bo, (float*)d_out);
}

// Round 13
// 811.203 us; speedup vs baseline: 2.5397x; 2.5397x over previous
//
#include <hip/hip_runtime.h>
#include <math.h>

#define BS   2048
#define SEQ  50
#define NPOS (BS * SEQ)

__device__ __forceinline__ float sigf(float x) { return 1.0f / (1.0f + __expf(-x)); }
__device__ __forceinline__ float tanhfast(float x) {
    float e = __expf(2.0f * x);
    return 1.0f - 2.0f / (e + 1.0f);
}

// ---- macro toolkit: named-SSA values only (NO private arrays) -------------
#define FMA4(A, X, W) \
    A = fmaf((X).x, (W).x, A); A = fmaf((X).y, (W).y, A); \
    A = fmaf((X).z, (W).z, A); A = fmaf((X).w, (W).w, A);

#define LD16(P, N) \
    float4 N##0=(P)[0],  N##1=(P)[1],  N##2=(P)[2],  N##3=(P)[3], \
           N##4=(P)[4],  N##5=(P)[5],  N##6=(P)[6],  N##7=(P)[7], \
           N##8=(P)[8],  N##9=(P)[9],  N##10=(P)[10],N##11=(P)[11], \
           N##12=(P)[12],N##13=(P)[13],N##14=(P)[14],N##15=(P)[15];

// ---------------------------------------------------------------------------
// prep_w (R10 verbatim): transpose W_ih/W_hh into wave-contiguous layouts.
// ---------------------------------------------------------------------------
__global__ __launch_bounds__(512) void prep_w(
    const float* __restrict__ Wih, const float* __restrict__ Whh,
    float4* __restrict__ wiT, float4* __restrict__ whT)
{
    const int t = threadIdx.x;
    const int gq = t >> 2, kq = t & 3;
    const int b = blockIdx.x;
    if (b < 16) {
        const int g = b >> 2, kk = b & 3;
        wiT[b * 512 + t] = *(const float4*)&Wih[(4*gq + g) * 64 + kq * 16 + kk * 4];
    } else {
        const int c = b - 16;
        const int g = c >> 3, kk = c & 7;
        whT[c * 512 + t] = *(const float4*)&Whh[(4*gq + g) * 128 + kq * 32 + kk * 4];
    }
}

// ---------------------------------------------------------------------------
// Kernel A = R6/R8 proven single-wave design (DO NOT split Q/V across waves:
// R12's 2-wave variant got 160 VGPR / 12% occupancy / 5x regression) + a
// register software-pipeline: prefetch position p+grid's inputs during p's
// compute (consumer is 2 barriers later -> global latency fully hidden).
// ---------------------------------------------------------------------------
__global__
__attribute__((amdgpu_flat_work_group_size(64, 64), amdgpu_waves_per_eu(2, 2)))
void edge_attn_ctx(
    const float* __restrict__ seqs,   // [BS,SEQ,3,3,6]
    const float* __restrict__ ets,    // [BS,SEQ,3,3,4]
    const int*   __restrict__ masks,  // [BS,SEQ,3,3]
    const float* __restrict__ Wf, const float* __restrict__ bf,
    const float* __restrict__ Wk, const float* __restrict__ bk,
    const float* __restrict__ Wq, const float* __restrict__ bq,
    const float* __restrict__ Wv, const float* __restrict__ bv,
    float* __restrict__ ctx)          // [BS,SEQ,64]
{
    const int o = threadIdx.x;

    const float4* qp = (const float4*)&Wq[o * 64];
    LD16(qp, wq)
    const float4* vp = (const float4*)&Wv[o * 64];
    LD16(vp, wv)

    const float* wfp = &Wf[o * 19];
    float wf0=wfp[0], wf1=wfp[1], wf2=wfp[2], wf3=wfp[3], wf4=wfp[4], wf5=wfp[5],
          wf6=wfp[6], wf7=wfp[7], wf8=wfp[8], wf9=wfp[9];
    float wfe0=wfp[10], wfe1=wfp[11], wfe2=wfp[12], wfe3=wfp[13], wfe4=wfp[14],
          wfe5=wfp[15], wfe6=wfp[16], wfe7=wfp[17], wfe8=wfp[18];
    const float* wkp = &Wk[o * 6];
    float wk0=wkp[0], wk1=wkp[1], wk2=wkp[2], wk3=wkp[3], wk4=wkp[4], wk5=wkp[5];

    const float bfr = bf[o], bkr = bk[o], bqr = bq[o], bvr = bv[o];

    __shared__ float s_seq[54];
    __shared__ float s_et[36];
    __shared__ int   s_mask[9];
    __shared__ float s_edge[9 * 64];

    // prime the software pipeline (grid divides NPOS exactly: 4096*25)
    int p = blockIdx.x;
    float pf_a = 0.f, pf_b = 0.f; int pf_m = 0;
    if (o < 54) pf_a = seqs[p * 54 + o];
    if (o < 36) pf_b = ets[p * 36 + o];
    if (o < 9)  pf_m = masks[p * 9 + o];

    for (; p < NPOS; p += gridDim.x) {
        if (o < 54) s_seq[o]  = pf_a;
        if (o < 36) s_et[o]   = pf_b;
        if (o < 9)  s_mask[o] = pf_m;
        __syncthreads();

        {   // issue next position's loads now; consumed after 2 barriers
            const int pn = p + gridDim.x;
            if (pn < NPOS) {
                if (o < 54) pf_a = seqs[pn * 54 + o];
                if (o < 36) pf_b = ets[pn * 36 + o];
                if (o < 9)  pf_m = masks[pn * 9 + o];
            }
        }

        float wfe[9] = {wfe0,wfe1,wfe2,wfe3,wfe4,wfe5,wfe6,wfe7,wfe8};
        #pragma unroll
        for (int e = 0; e < 9; ++e) {
            float v = bfr + wfe[e];
            v = fmaf(s_seq[e*6+0], wf0, v);
            v = fmaf(s_seq[e*6+1], wf1, v);
            v = fmaf(s_seq[e*6+2], wf2, v);
            v = fmaf(s_seq[e*6+3], wf3, v);
            v = fmaf(s_seq[e*6+4], wf4, v);
            v = fmaf(s_seq[e*6+5], wf5, v);
            v = fmaf(s_et[e*4+0],  wf6, v);
            v = fmaf(s_et[e*4+1],  wf7, v);
            v = fmaf(s_et[e*4+2],  wf8, v);
            v = fmaf(s_et[e*4+3],  wf9, v);
            s_edge[e * 64 + o] = v;
        }
        float key = bkr;
        key = fmaf(s_seq[24], wk0, key);
        key = fmaf(s_seq[25], wk1, key);
        key = fmaf(s_seq[26], wk2, key);
        key = fmaf(s_seq[27], wk3, key);
        key = fmaf(s_seq[28], wk4, key);
        key = fmaf(s_seq[29], wk5, key);
        __syncthreads();

        float vv[9], att[9];
        #pragma unroll
        for (int e = 0; e < 9; ++e) {
            const float4* ep = (const float4*)&s_edge[e * 64];
            float q0 = 0.f, q1 = 0.f, v0 = 0.f, v1 = 0.f;
            {
                float4 t;
                t=ep[0];  FMA4(q0,t,wq0)  FMA4(v0,t,wv0)
                t=ep[1];  FMA4(q1,t,wq1)  FMA4(v1,t,wv1)
                t=ep[2];  FMA4(q0,t,wq2)  FMA4(v0,t,wv2)
                t=ep[3];  FMA4(q1,t,wq3)  FMA4(v1,t,wv3)
                t=ep[4];  FMA4(q0,t,wq4)  FMA4(v0,t,wv4)
                t=ep[5];  FMA4(q1,t,wq5)  FMA4(v1,t,wv5)
                t=ep[6];  FMA4(q0,t,wq6)  FMA4(v0,t,wv6)
                t=ep[7];  FMA4(q1,t,wq7)  FMA4(v1,t,wv7)
                t=ep[8];  FMA4(q0,t,wq8)  FMA4(v0,t,wv8)
                t=ep[9];  FMA4(q1,t,wq9)  FMA4(v1,t,wv9)
                t=ep[10]; FMA4(q0,t,wq10) FMA4(v0,t,wv10)
                t=ep[11]; FMA4(q1,t,wq11) FMA4(v1,t,wv11)
                t=ep[12]; FMA4(q0,t,wq12) FMA4(v0,t,wv12)
                t=ep[13]; FMA4(q1,t,wq13) FMA4(v1,t,wv13)
                t=ep[14]; FMA4(q0,t,wq14) FMA4(v0,t,wv14)
                t=ep[15]; FMA4(q1,t,wq15) FMA4(v1,t,wv15)
            }
            float qq = bqr + q0 + q1;
            vv[e] = bvr + v0 + v1;
            float a_ = key * qq;
            a_ += __shfl_xor(a_, 8, 16);
            a_ += __shfl_xor(a_, 4, 16);
            a_ += __shfl_xor(a_, 2, 16);
            a_ += __shfl_xor(a_, 1, 16);
            att[e] = a_ * 0.25f;   // / sqrt(16)
        }

        float mx = -3.0e38f;
        #pragma unroll
        for (int e = 0; e < 9; ++e) {
            att[e] = (s_mask[e] == 0) ? -1.0e10f : att[e];
            mx = fmaxf(mx, att[e]);
        }
        float ssum = 0.f;
        #pragma unroll
        for (int e = 0; e < 9; ++e) { att[e] = __expf(att[e] - mx); ssum += att[e]; }
        float inv = 1.f / ssum;
        float acc = 0.f;
        #pragma unroll
        for (int e = 0; e < 9; ++e) acc = fmaf(att[e], vv[e], acc);
        ctx[p * 64 + o] = acc * inv;
        __syncthreads();
    }
}

// ---------------------------------------------------------------------------
// Kernel C (R10 verbatim + ctx-prefetch): G=4 x S=4, R=8, 256 blk x 512 thr;
// coalesced transposed weight stream with DYNAMIC (kk+s)&mask rotation.
// Do NOT staticize addressing (R11: hoist -> 128 VGPR + 185 MB spill);
// do NOT stream scattered from d_in (R6/R8: 4x L2 line inflation).
// ---------------------------------------------------------------------------
#define XROW 80    // floats per s_x row (quarters of 16 at cols 0/20/40/60)
#define HROWF 144  // floats per s_h row (quarters of 32 at cols 0/36/72/108)
#define SGS  516   // s_g row stride (floats)

#define XG(kk) { \
    const int kk2 = ((kk) + s) & 3; \
    const int wb = kk2 * 512 + t; \
    float4 w0_ = wiT[0*2048 + wb]; \
    float4 w1_ = wiT[1*2048 + wb]; \
    float4 w2_ = wiT[2*2048 + wb]; \
    float4 w3_ = wiT[3*2048 + wb]; \
    float4 x_; \
    x_ = sx4[0*20 + kq5 + kk2]; FMA4(A00,x_,w0_) FMA4(A10,x_,w1_) FMA4(A20,x_,w2_) FMA4(A30,x_,w3_) \
    x_ = sx4[1*20 + kq5 + kk2]; FMA4(A01,x_,w0_) FMA4(A11,x_,w1_) FMA4(A21,x_,w2_) FMA4(A31,x_,w3_) \
    x_ = sx4[2*20 + kq5 + kk2]; FMA4(A02,x_,w0_) FMA4(A12,x_,w1_) FMA4(A22,x_,w2_) FMA4(A32,x_,w3_) \
    x_ = sx4[3*20 + kq5 + kk2]; FMA4(A03,x_,w0_) FMA4(A13,x_,w1_) FMA4(A23,x_,w2_) FMA4(A33,x_,w3_) \
    x_ = sx4[4*20 + kq5 + kk2]; FMA4(A04,x_,w0_) FMA4(A14,x_,w1_) FMA4(A24,x_,w2_) FMA4(A34,x_,w3_) \
    x_ = sx4[5*20 + kq5 + kk2]; FMA4(A05,x_,w0_) FMA4(A15,x_,w1_) FMA4(A25,x_,w2_) FMA4(A35,x_,w3_) \
    x_ = sx4[6*20 + kq5 + kk2]; FMA4(A06,x_,w0_) FMA4(A16,x_,w1_) FMA4(A26,x_,w2_) FMA4(A36,x_,w3_) \
    x_ = sx4[7*20 + kq5 + kk2]; FMA4(A07,x_,w0_) FMA4(A17,x_,w1_) FMA4(A27,x_,w2_) FMA4(A37,x_,w3_) }

#define HG(kk) { \
    const int kk2 = ((kk) + s) & 7; \
    const int wb = kk2 * 512 + t; \
    float4 w0_ = whT[0*4096 + wb]; \
    float4 w1_ = whT[1*4096 + wb]; \
    float4 w2_ = whT[2*4096 + wb]; \
    float4 w3_ = whT[3*4096 + wb]; \
    float4 h_; \
    h_ = sh4[0*36 + kq9 + kk2]; FMA4(A00,h_,w0_) FMA4(A10,h_,w1_) FMA4(A20,h_,w2_) FMA4(A30,h_,w3_) \
    h_ = sh4[1*36 + kq9 + kk2]; FMA4(A01,h_,w0_) FMA4(A11,h_,w1_) FMA4(A21,h_,w2_) FMA4(A31,h_,w3_) \
    h_ = sh4[2*36 + kq9 + kk2]; FMA4(A02,h_,w0_) FMA4(A12,h_,w1_) FMA4(A22,h_,w2_) FMA4(A32,h_,w3_) \
    h_ = sh4[3*36 + kq9 + kk2]; FMA4(A03,h_,w0_) FMA4(A13,h_,w1_) FMA4(A23,h_,w2_) FMA4(A33,h_,w3_) \
    h_ = sh4[4*36 + kq9 + kk2]; FMA4(A04,h_,w0_) FMA4(A14,h_,w1_) FMA4(A24,h_,w2_) FMA4(A34,h_,w3_) \
    h_ = sh4[5*36 + kq9 + kk2]; FMA4(A05,h_,w0_) FMA4(A15,h_,w1_) FMA4(A25,h_,w2_) FMA4(A35,h_,w3_) \
    h_ = sh4[6*36 + kq9 + kk2]; FMA4(A06,h_,w0_) FMA4(A16,h_,w1_) FMA4(A26,h_,w2_) FMA4(A36,h_,w3_) \
    h_ = sh4[7*36 + kq9 + kk2]; FMA4(A07,h_,w0_) FMA4(A17,h_,w1_) FMA4(A27,h_,w2_) FMA4(A37,h_,w3_) }

#define RED2(A) A += __shfl_xor(A, 1); A += __shfl_xor(A, 2);
#define SELL(g) (kq == 0 ? A##g##0 : kq == 1 ? A##g##1 : kq == 2 ? A##g##2 : A##g##3)
#define SELH(g) (kq == 0 ? A##g##4 : kq == 1 ? A##g##5 : kq == 2 ? A##g##6 : A##g##7)

__global__ __launch_bounds__(512)
void lstm_out(
    const float*  __restrict__ ctx,   // [BS,SEQ,64]
    const float4* __restrict__ wiT,   // [(g*4+kk)*512 + t]
    const float4* __restrict__ whT,   // [(g*8+kk)*512 + t]
    const float*  __restrict__ b_ih, const float* __restrict__ b_hh,
    const float*  __restrict__ W_out, const float* __restrict__ b_out,
    float* __restrict__ out)          // [BS,64]
{
    const int t    = threadIdx.x;
    const int gq   = t >> 2;          // gate quad 0..127 -> gates 4gq..4gq+3
    const int kq   = t & 3;           // k-quarter
    const int kq5  = kq * 5;          // x quarter offset (float4s)
    const int kq9  = kq * 9;          // h quarter offset (float4s)
    const int row0 = blockIdx.x * 8;
    const int r2   = t >> 6;          // pointwise/staging row 0..7
    const int m    = t & 63;          // pointwise elem (m and m+64)

    // pointwise biases (gate order i,f,g,o = rows 0/128/256/384)
    const float bi0 = b_ih[m]       + b_hh[m];
    const float bf0 = b_ih[128 + m] + b_hh[128 + m];
    const float bg0 = b_ih[256 + m] + b_hh[256 + m];
    const float bo0 = b_ih[384 + m] + b_hh[384 + m];
    const float bi1 = b_ih[64 + m]  + b_hh[64 + m];
    const float bf1 = b_ih[192 + m] + b_hh[192 + m];
    const float bg1 = b_ih[320 + m] + b_hh[320 + m];
    const float bo1 = b_ih[448 + m] + b_hh[448 + m];

    __shared__ float s_x[8 * XROW];
    __shared__ float s_h[8 * HROWF];
    __shared__ float s_g[8 * SGS];

    const float4* sx4 = (const float4*)s_x;
    const float4* sh4 = (const float4*)s_h;

    const int xcol  = r2 * XROW + (m >> 4) * 20 + (m & 15);
    const int hcol0 = r2 * HROWF + (m >> 5) * 36 + (m & 31);
    const int hcol1 = r2 * HROWF + (2 + (m >> 5)) * 36 + (m & 31);

    const float* ctxp = &ctx[(row0 + r2) * (SEQ * 64) + m];
    float xnext = ctxp[0];            // prime the ctx pipeline

    float c0 = 0.f, c1 = 0.f;

    for (int s = 0; s < SEQ; ++s) {
        s_x[xcol] = xnext;
        __syncthreads();

        if (s + 1 < SEQ) xnext = ctxp[(s + 1) * 64];   // hidden: used next iter

        float A00=0.f,A01=0.f,A02=0.f,A03=0.f,A04=0.f,A05=0.f,A06=0.f,A07=0.f;
        float A10=0.f,A11=0.f,A12=0.f,A13=0.f,A14=0.f,A15=0.f,A16=0.f,A17=0.f;
        float A20=0.f,A21=0.f,A22=0.f,A23=0.f,A24=0.f,A25=0.f,A26=0.f,A27=0.f;
        float A30=0.f,A31=0.f,A32=0.f,A33=0.f,A34=0.f,A35=0.f,A36=0.f,A37=0.f;

        XG(0) XG(1) XG(2) XG(3)
        if (s > 0) {
            HG(0) HG(1) HG(2) HG(3) HG(4) HG(5) HG(6) HG(7)
        }

        RED2(A00) RED2(A01) RED2(A02) RED2(A03) RED2(A04) RED2(A05) RED2(A06) RED2(A07)
        RED2(A10) RED2(A11) RED2(A12) RED2(A13) RED2(A14) RED2(A15) RED2(A16) RED2(A17)
        RED2(A20) RED2(A21) RED2(A22) RED2(A23) RED2(A24) RED2(A25) RED2(A26) RED2(A27)
        RED2(A30) RED2(A31) RED2(A32) RED2(A33) RED2(A34) RED2(A35) RED2(A36) RED2(A37)

        {   // lane kq writes rows kq and kq+4, gates 4gq..4gq+3 (b128 each)
            float4 glo = make_float4(SELL(0), SELL(1), SELL(2), SELL(3));
            float4 ghi = make_float4(SELH(0), SELH(1), SELH(2), SELH(3));
            *(float4*)&s_g[kq * SGS + (gq << 2)]       = glo;
            *(float4*)&s_g[(kq + 4) * SGS + (gq << 2)] = ghi;
        }
        __syncthreads();

        {   // pointwise for (r2, m) and (r2, m+64); c-state in registers
            const float* g0 = &s_g[r2 * SGS];
            float ig = sigf(g0[m] + bi0);
            float fg = sigf(g0[128 + m] + bf0);
            float gt = tanhfast(g0[256 + m] + bg0);
            float og = sigf(g0[384 + m] + bo0);
            c0 = fmaf(fg, c0, ig * gt);
            s_h[hcol0] = og * tanhfast(c0);

            float ih = sigf(g0[64 + m] + bi1);
            float fh = sigf(g0[192 + m] + bf1);
            float gh = tanhfast(g0[320 + m] + bg1);
            float oh = sigf(g0[448 + m] + bo1);
            c1 = fmaf(fh, c1, ih * gh);
            s_h[hcol1] = oh * tanhfast(c1);
        }
        __syncthreads();
    }

    // epilogue: out[row0+r2][m] = b_out[m] + h[r2] . W_out[m]
    {
        float acc = b_out[m];
        const float4* wp = (const float4*)&W_out[m * 128];
        #pragma unroll
        for (int q = 0; q < 4; ++q)
            #pragma unroll
            for (int i = 0; i < 8; ++i) {
                float4 h4 = sh4[r2 * 36 + q * 9 + i];   // broadcast read
                float4 w4 = wp[q * 8 + i];
                FMA4(acc, h4, w4)
            }
        out[(row0 + r2) * 64 + m] = acc;
    }
}

// ---------------------------------------------------------------------------
extern "C" void kernel_launch(void* const* d_in, const int* in_sizes, int n_in,
                              void* d_out, int out_size, void* d_ws, size_t ws_size,
                              hipStream_t stream) {
    (void)in_sizes; (void)n_in; (void)out_size; (void)ws_size;
    const float* seqs  = (const float*)d_in[0];
    const float* ets   = (const float*)d_in[1];
    const int*   masks = (const int*)d_in[2];
    const float* Wf  = (const float*)d_in[3];
    const float* bf  = (const float*)d_in[4];
    const float* Wk  = (const float*)d_in[5];
    const float* bk  = (const float*)d_in[6];
    const float* Wq  = (const float*)d_in[7];
    const float* bq  = (const float*)d_in[8];
    const float* Wv  = (const float*)d_in[9];
    const float* bv  = (const float*)d_in[10];
    const float* Wih = (const float*)d_in[11];
    const float* Whh = (const float*)d_in[12];
    const float* bih = (const float*)d_in[13];
    const float* bhh = (const float*)d_in[14];
    const float* Wo  = (const float*)d_in[15];
    const float* bo  = (const float*)d_in[16];

    // ws layout: wiT 128K | whT 256K | ctx 26.2M
    char* ws = (char*)d_ws;
    float4* wiT = (float4*)(ws);
    float4* whT = (float4*)(ws + 131072);
    float*  ctx = (float*) (ws + 131072 + 262144);

    hipLaunchKernelGGL(prep_w, dim3(48), dim3(512), 0, stream,
                       Wih, Whh, wiT, whT);
    hipLaunchKernelGGL(edge_attn_ctx, dim3(4096), dim3(64), 0, stream,
                       seqs, ets, masks, Wf, bf, Wk, bk, Wq, bq, Wv, bv, ctx);
    hipLaunchKernelGGL(lstm_out, dim3(256), dim3(512), 0, stream,
                       ctx, wiT, whT, bih, bhh, Wo, bo, (float*)d_out);
}